// Round 18
// baseline (73.217 us; speedup 1.0000x reference)
//
#include <hip/hip_runtime.h>
#include <hip/hip_fp16.h>

// retina_polar2: log-polar glimpse sampling + 10x10 avg-pool
// x: [64,3,512,512] f32 | l_t_prev: [64,2] f32 | grid_2d: [320,640,2] f32
// out: [64,3,32,64] f32
//
// Round-18 = r17 pipeline deepened to QUAD slots per block:
//  - cold stage-stall + tables/bbox paid once per 4 theta-slices (was 2);
//    36 blocks/image (2304 total, 9/CU queue, 4 resident).
//  - steady state per slot: [issue loads(s+1) | rebuild sctab(s+1) |
//    gather(s)] -> barrier -> [out(s) | write tile(s+1)] -> barrier.
//  - PITCH 67->66 (conflicts proven off-critical-path in r14) + lazily
//    double-buffered sctab keep LDS at 39,952 B -> 4 blocks/CU.
//  - gather item loop: div/mod replaced by increment-with-wrap.
// Kept: f16 packed-lerp tile (one ds_read_b64/tap), separable grid in
// LDS (zero-VMEM gather), analytic bbox, interior fast path, bijective
// ds_write_b128 accumulation (no atomics).

#define HI_ 512
#define WI_ 512
#define B_  64
#define PLANE_ (HI_ * WI_)
#define PITCH 66
#define TILEPIX (64 * PITCH)   // 4224 px * 8 B = 33792 B

__device__ __forceinline__ __half2 u2h(unsigned u) {
    return *reinterpret_cast<const __half2*>(&u);
}

__device__ __forceinline__ void store_px(__half* __restrict__ simg, int pix,
                                         float a, float b, float c) {
    const __half2 h01 = __floats2half2_rn(a, b);
    const __half  h2  = __float2half_rn(c);
    uint2 u;
    u.x = *reinterpret_cast<const unsigned*>(&h01);
    u.y = (unsigned)*reinterpret_cast<const unsigned short*>(&h2);
    *reinterpret_cast<uint2*>(simg + 4 * pix) = u;   // one ds_write_b64
}

template<int W0, int G, int T, bool INT>
__device__ __forceinline__ void gatherLoop(
    const int tid,
    const __half* __restrict__ simg,
    float* __restrict__ sacc,
    const float* __restrict__ rtab,
    const float2* __restrict__ sct,
    const float sx, const float sy,
    const int xs4, const int y_lo, const int wmax, const int hmax)
{
    constexpr int ITEMS = T * G;
    constexpr int DW = 256 / T, DT = 256 % T;
    int tl  = tid % T;     // once (compile-time magic mul)
    int win = tid / T;
    for (int it = tid; it < ITEMS; it += 256) {
        const float2 sc = sct[tl];
        const int rbase = win * 10;

        int     pp [10];
        __half2 wxh[10], wyh[10];
        #pragma unroll
        for (int j = 0; j < 10; ++j) {
            const float r2 = rtab[rbase + j];
            float ix = fmaf(r2, sc.x, sx);
            float iy = fmaf(r2, sc.y, sy);
            if (!INT) {
                ix = fminf(fmaxf(ix, 0.0f), 511.0f);
                iy = fminf(fmaxf(iy, 0.0f), 511.0f);
            }
            const float x0f = floorf(ix);
            const float y0f = floorf(iy);
            int col = (int)x0f - xs4;
            int row = (int)y0f - y_lo;
            if (!INT) {
                col = min(max(col, 0), wmax);
                row = min(max(row, 0), hmax);
            }
            pp [j] = row * PITCH + col;
            wxh[j] = __float2half2_rn(ix - x0f);
            wyh[j] = __float2half2_rn(iy - y0f);
        }

        float s0 = 0.0f, s1 = 0.0f, s2 = 0.0f;
        #pragma unroll
        for (int hh = 0; hh < 2; ++hh) {
            uint2 q00[5], q01[5], q10[5], q11[5];
            #pragma unroll
            for (int j = 0; j < 5; ++j) {
                const int p = pp[hh * 5 + j];
                q00[j] = *reinterpret_cast<const uint2*>(simg + 4 * p);
                q01[j] = *reinterpret_cast<const uint2*>(simg + 4 * (p + 1));
                q10[j] = *reinterpret_cast<const uint2*>(simg + 4 * (p + PITCH));
                q11[j] = *reinterpret_cast<const uint2*>(simg + 4 * (p + PITCH + 1));
            }
            #pragma unroll
            for (int j = 0; j < 5; ++j) {
                const int rr = hh * 5 + j;
                const __half2 wx2 = wxh[rr], wy2 = wyh[rr];
                const __half2 a00 = u2h(q00[j].x), a01 = u2h(q01[j].x);
                const __half2 a10 = u2h(q10[j].x), a11 = u2h(q11[j].x);
                __half2 topA = __hfma2(wx2, __hsub2(a01, a00), a00);
                __half2 botA = __hfma2(wx2, __hsub2(a11, a10), a10);
                __half2 valA = __hfma2(wy2, __hsub2(botA, topA), topA);
                const __half2 b00 = u2h(q00[j].y), b01 = u2h(q01[j].y);
                const __half2 b10 = u2h(q10[j].y), b11 = u2h(q11[j].y);
                __half2 topB = __hfma2(wx2, __hsub2(b01, b00), b00);
                __half2 botB = __hfma2(wx2, __hsub2(b11, b10), b10);
                __half2 valB = __hfma2(wy2, __hsub2(botB, topB), topB);

                const float2 fA = __half22float2(valA);
                s0 += fA.x;
                s1 += fA.y;
                s2 += __low2float(valB);
            }
        }
        *reinterpret_cast<float4*>(&sacc[it * 4]) =
            make_float4(s0, s1, s2, 0.0f);

        tl += DT; win += DW;
        if (tl >= T) { tl -= T; ++win; }
    }
}

template<int W0, int G, int T>
__device__ __forceinline__ void band4(
    const int b, const int quad,
    const float* __restrict__ x,
    float* __restrict__ out,
    const float sx, const float sy,
    __half*  __restrict__ simg,
    float*   __restrict__ sacc,
    float*   __restrict__ rtab,
    float2*  __restrict__ sct,     // 2*T entries (dbuf)
    int*     __restrict__ sbb)     // 4 slots x 5 ints
{
    constexpr int TC   = T / 10;
    constexpr int ACCN = 3 * G * TC;
    const int tid   = threadIdx.x;
    const int slot0 = quad * 4;
    const int lane16 = tid & 15;
    const int rowB   = tid >> 4;

    const float CT  = 6.283185307179586f / 640.0f;
    const float LN001 = -4.605170185988091f;          // ln 0.01
    const float LSTEP = 4.0943445622221004f / 319.0f; // ln 60 / 319

    // ---- prologue: rtab, sctab buf0 (slot0), 4 bboxes ----
    if (tid < G * 10)
        rtab[tid] = 256.0f * expf(fmaf((float)(W0 * 10 + tid), LSTEP, LN001));
    if (tid >= 128 && tid < 128 + T) {
        const int u = tid - 128;
        const float th = (float)(slot0 * T + u) * CT;
        sct[u] = make_float2(sinf(th), cosf(th));
    }
    if (tid < 4) {
        const int th0 = (slot0 + tid) * T;
        const float tha = th0 * CT, thb = (th0 + T - 1) * CT;
        const float r_lo = expf(fmaf((float)(10 * W0),           LSTEP, LN001));
        const float r_hi = expf(fmaf((float)(10 * (W0 + G) - 1), LSTEP, LN001));
        const float plo = 256.0f * r_lo, phi = 256.0f * r_hi;
        const float sa = sinf(tha), sb = sinf(thb);
        const float ca = cosf(tha), cb = cosf(thb);
        const float smax = (tha < 1.5707965f && thb > 1.5707962f) ?  1.0f : fmaxf(sa, sb);
        const float smin = (tha < 4.7123892f && thb > 4.7123888f) ? -1.0f : fminf(sa, sb);
        const float cmax = fmaxf(ca, cb);
        const float cmin = (tha < 3.1415928f && thb > 3.1415925f) ? -1.0f : fminf(ca, cb);
        const float ixmin = fminf(fminf(plo*smin, phi*smin), fminf(plo*smax, phi*smax)) + sx;
        const float ixmax = fmaxf(fmaxf(plo*smin, phi*smin), fmaxf(plo*smax, phi*smax)) + sx;
        const float iymin = fminf(fminf(plo*cmin, phi*cmin), fminf(plo*cmax, phi*cmax)) + sy;
        const float iymax = fmaxf(fmaxf(plo*cmin, phi*cmin), fmaxf(plo*cmax, phi*cmax)) + sy;
        const int x_lo = max(0, (int)floorf(ixmin - 0.5f));
        const int x_hi = min(511, (int)ceilf(ixmax + 0.5f));
        const int y_lo = max(0, (int)floorf(iymin - 0.5f));
        const int y_hi = min(511, (int)ceilf(iymax + 0.5f));
        int* o = sbb + 5 * tid;
        o[0] = x_lo & ~3;
        o[1] = y_lo;
        o[2] = min(16, ((x_hi + 1 - (x_lo & ~3)) >> 2) + 1);
        o[3] = min(64, y_hi - y_lo + 2);
        o[4] = ((ixmin > 1.0f) && (ixmax < 510.0f) &&
                (iymin > 1.0f) && (iymax < 510.0f)) ? 1 : 0;
    }
    __syncthreads();

    const float* __restrict__ xb = x + (size_t)b * 3 * PLANE_;

    // ---- stage slot0 (issue upfront + write) ----
    {
        const int xs4 = sbb[0], y_lo = sbb[1], W4 = sbb[2], H = sbb[3];
        const int xb0 = xs4 + (lane16 << 2);
        if (lane16 < W4) {
            if (xb0 <= 508) {
                float4 v0[4], v1[4], v2[4];
                int rw[4];
                #pragma unroll
                for (int k = 0; k < 4; ++k) {
                    rw[k] = rowB + 16 * k;
                    if (rw[k] < H) {
                        const int ys = min(y_lo + rw[k], 511);
                        const float* __restrict__ r0 = xb + ys * 512 + xb0;
                        v0[k] = *reinterpret_cast<const float4*>(r0);
                        v1[k] = *reinterpret_cast<const float4*>(r0 + PLANE_);
                        v2[k] = *reinterpret_cast<const float4*>(r0 + 2 * PLANE_);
                    }
                }
                #pragma unroll
                for (int k = 0; k < 4; ++k) {
                    if (rw[k] < H) {
                        const int pix0 = rw[k] * PITCH + (lane16 << 2);
                        const float* a0 = reinterpret_cast<const float*>(&v0[k]);
                        const float* a1 = reinterpret_cast<const float*>(&v1[k]);
                        const float* a2 = reinterpret_cast<const float*>(&v2[k]);
                        #pragma unroll
                        for (int p = 0; p < 4; ++p)
                            store_px(simg, pix0 + p, a0[p], a1[p], a2[p]);
                    }
                }
            } else {
                #pragma unroll
                for (int k = 0; k < 4; ++k) {
                    const int rw = rowB + 16 * k;
                    if (rw < H) {
                        const int ys = min(y_lo + rw, 511);
                        const float* __restrict__ r0 = xb + ys * 512;
                        const int pix0 = rw * PITCH + (lane16 << 2);
                        #pragma unroll
                        for (int p = 0; p < 4; ++p) {
                            const int xs = min(xb0 + p, 511);
                            store_px(simg, pix0 + p,
                                     r0[xs], r0[PLANE_ + xs], r0[2 * PLANE_ + xs]);
                        }
                    }
                }
            }
        }
    }
    __syncthreads();

    float4 e0[4], e1[4], e2[4];
    #pragma unroll 1
    for (int i = 0; i < 4; ++i) {
        const int* bb = sbb + 5 * i;
        const int* nb = sbb + 5 * (i + 1);   // valid when i<3
        bool main1 = false;
        int  xb1 = 0;
        if (i < 3) {
            // issue next slot's loads into registers (early)
            xb1   = nb[0] + (lane16 << 2);
            main1 = (lane16 < nb[2]) && (xb1 <= 508);
            if (main1) {
                #pragma unroll
                for (int k = 0; k < 4; ++k) {
                    const int rw = rowB + 16 * k;
                    if (rw < nb[3]) {
                        const int ys = min(nb[1] + rw, 511);
                        const float* __restrict__ r0 = xb + ys * 512 + xb1;
                        e0[k] = *reinterpret_cast<const float4*>(r0);
                        e1[k] = *reinterpret_cast<const float4*>(r0 + PLANE_);
                        e2[k] = *reinterpret_cast<const float4*>(r0 + 2 * PLANE_);
                    }
                }
            }
            // rebuild sctab for next slot into the other buffer
            if (tid >= 192 && tid < 192 + T) {
                const int u = tid - 192;
                const float th = (float)((slot0 + i + 1) * T + u) * CT;
                sct[((i + 1) & 1) * T + u] = make_float2(sinf(th), cosf(th));
            }
        }

        // gather slot i (hides next slot's HBM latency)
        {
            const int wmax = (bb[2] << 2) - 2, hmax = bb[3] - 2;
            if (bb[4])
                gatherLoop<W0, G, T, true >(tid, simg, sacc, rtab,
                    reinterpret_cast<const float2*>(sct) + (i & 1) * T,
                    sx, sy, bb[0], bb[1], wmax, hmax);
            else
                gatherLoop<W0, G, T, false>(tid, simg, sacc, rtab,
                    reinterpret_cast<const float2*>(sct) + (i & 1) * T,
                    sx, sy, bb[0], bb[1], wmax, hmax);
        }
        __syncthreads();

        // out(slot i) || write tile(slot i+1)
        if (tid < ACCN) {
            const int c   = tid / (G * TC);
            const int rem = tid - c * (G * TC);
            const int win = rem / TC;
            const int tc  = rem - win * TC;
            const int base = (win * T + tc * 10) * 4 + c;
            float s = 0.0f;
            #pragma unroll
            for (int ph = 0; ph < 10; ++ph)
                s += sacc[base + ph * 4];
            out[(((size_t)b * 3 + c) * 32 + W0 + win) * 64 + (slot0 + i) * TC + tc] =
                s * 0.01f;
        }
        if (i < 3 && lane16 < nb[2]) {
            const int Hb = nb[3];
            if (main1) {
                #pragma unroll
                for (int k = 0; k < 4; ++k) {
                    const int rw = rowB + 16 * k;
                    if (rw < Hb) {
                        const int pix0 = rw * PITCH + (lane16 << 2);
                        const float* a0 = reinterpret_cast<const float*>(&e0[k]);
                        const float* a1 = reinterpret_cast<const float*>(&e1[k]);
                        const float* a2 = reinterpret_cast<const float*>(&e2[k]);
                        #pragma unroll
                        for (int p = 0; p < 4; ++p)
                            store_px(simg, pix0 + p, a0[p], a1[p], a2[p]);
                    }
                }
            } else {
                // rare right-edge: late scalar clamped loads
                #pragma unroll
                for (int k = 0; k < 4; ++k) {
                    const int rw = rowB + 16 * k;
                    if (rw < Hb) {
                        const int ys = min(nb[1] + rw, 511);
                        const float* __restrict__ r0 = xb + ys * 512;
                        const int pix0 = rw * PITCH + (lane16 << 2);
                        #pragma unroll
                        for (int p = 0; p < 4; ++p) {
                            const int xs = min(xb1 + p, 511);
                            store_px(simg, pix0 + p,
                                     r0[xs], r0[PLANE_ + xs], r0[2 * PLANE_ + xs]);
                        }
                    }
                }
            }
        }
        __syncthreads();
    }
}

__global__ __launch_bounds__(256, 4) void retina_polar_staged(
    const float* __restrict__ x,
    const float* __restrict__ lt,
    const float* __restrict__ grid,   // unused: grid is separable, rebuilt in LDS
    float* __restrict__ out)
{
    __shared__ __half  simg[TILEPIX * 4];   // 33792 B
    __shared__ float   sacc[1280];          //  5120 B
    __shared__ float   rtab[80];            //   320 B
    __shared__ float2  sct[80];             //   640 B (2 buffers x T<=40)
    __shared__ int     sbb[20];             //    80 B  -> total 39952 B

    const int bid = blockIdx.x;
    const int b   = bid / 36;
    const int r   = bid - b * 36;
    const float sx = fmaf(lt[b * 2 + 0], 256.0f, 255.5f);
    const float sy = fmaf(lt[b * 2 + 1], 256.0f, 255.5f);

    if      (r <  4) band4< 0, 8, 40>(b, r,      x, out, sx, sy, simg, sacc, rtab, sct, sbb);
    else if (r <  8) band4< 8, 7, 40>(b, r - 4,  x, out, sx, sy, simg, sacc, rtab, sct, sbb);
    else if (r < 12) band4<15, 5, 40>(b, r - 8,  x, out, sx, sy, simg, sacc, rtab, sct, sbb);
    else if (r < 16) band4<20, 4, 40>(b, r - 12, x, out, sx, sy, simg, sacc, rtab, sct, sbb);
    else if (r < 20) band4<24, 3, 40>(b, r - 16, x, out, sx, sy, simg, sacc, rtab, sct, sbb);
    else if (r < 24) band4<27, 2, 40>(b, r - 20, x, out, sx, sy, simg, sacc, rtab, sct, sbb);
    else if (r < 28) band4<29, 1, 40>(b, r - 24, x, out, sx, sy, simg, sacc, rtab, sct, sbb);
    else             band4<30, 2, 20>(b, r - 28, x, out, sx, sy, simg, sacc, rtab, sct, sbb);
}

extern "C" void kernel_launch(void* const* d_in, const int* in_sizes, int n_in,
                              void* d_out, int out_size, void* d_ws, size_t ws_size,
                              hipStream_t stream)
{
    const float* x    = (const float*)d_in[0];
    const float* lt   = (const float*)d_in[1];
    const float* grid = (const float*)d_in[2];
    float* out        = (float*)d_out;

    retina_polar_staged<<<dim3(B_ * 36), dim3(256), 0, stream>>>(x, lt, grid, out);
}

// Round 19
// 72.783 us; speedup vs baseline: 1.0060x; 1.0060x over previous
//
#include <hip/hip_runtime.h>
#include <hip/hip_fp16.h>

// retina_polar2: log-polar glimpse sampling + 10x10 avg-pool
// x: [64,3,512,512] f32 | l_t_prev: [64,2] f32 | grid_2d: [320,640,2] f32
// out: [64,3,32,64] f32
//
// Round-18 = r17 pipeline deepened to QUAD slots per block:
//  - cold stage-stall + tables/bbox paid once per 4 theta-slices (was 2);
//    36 blocks/image (2304 total, 9/CU queue, 4 resident).
//  - steady state per slot: [issue loads(s+1) | rebuild sctab(s+1) |
//    gather(s)] -> barrier -> [out(s) | write tile(s+1)] -> barrier.
//  - PITCH 67->66 (conflicts proven off-critical-path in r14) + lazily
//    double-buffered sctab keep LDS at 39,952 B -> 4 blocks/CU.
//  - gather item loop: div/mod replaced by increment-with-wrap.
// Kept: f16 packed-lerp tile (one ds_read_b64/tap), separable grid in
// LDS (zero-VMEM gather), analytic bbox, interior fast path, bijective
// ds_write_b128 accumulation (no atomics).

#define HI_ 512
#define WI_ 512
#define B_  64
#define PLANE_ (HI_ * WI_)
#define PITCH 66
#define TILEPIX (64 * PITCH)   // 4224 px * 8 B = 33792 B

__device__ __forceinline__ __half2 u2h(unsigned u) {
    return *reinterpret_cast<const __half2*>(&u);
}

__device__ __forceinline__ void store_px(__half* __restrict__ simg, int pix,
                                         float a, float b, float c) {
    const __half2 h01 = __floats2half2_rn(a, b);
    const __half  h2  = __float2half_rn(c);
    uint2 u;
    u.x = *reinterpret_cast<const unsigned*>(&h01);
    u.y = (unsigned)*reinterpret_cast<const unsigned short*>(&h2);
    *reinterpret_cast<uint2*>(simg + 4 * pix) = u;   // one ds_write_b64
}

template<int W0, int G, int T, bool INT>
__device__ __forceinline__ void gatherLoop(
    const int tid,
    const __half* __restrict__ simg,
    float* __restrict__ sacc,
    const float* __restrict__ rtab,
    const float2* __restrict__ sct,
    const float sx, const float sy,
    const int xs4, const int y_lo, const int wmax, const int hmax)
{
    constexpr int ITEMS = T * G;
    constexpr int DW = 256 / T, DT = 256 % T;
    int tl  = tid % T;     // once (compile-time magic mul)
    int win = tid / T;
    for (int it = tid; it < ITEMS; it += 256) {
        const float2 sc = sct[tl];
        const int rbase = win * 10;

        int     pp [10];
        __half2 wxh[10], wyh[10];
        #pragma unroll
        for (int j = 0; j < 10; ++j) {
            const float r2 = rtab[rbase + j];
            float ix = fmaf(r2, sc.x, sx);
            float iy = fmaf(r2, sc.y, sy);
            if (!INT) {
                ix = fminf(fmaxf(ix, 0.0f), 511.0f);
                iy = fminf(fmaxf(iy, 0.0f), 511.0f);
            }
            const float x0f = floorf(ix);
            const float y0f = floorf(iy);
            int col = (int)x0f - xs4;
            int row = (int)y0f - y_lo;
            if (!INT) {
                col = min(max(col, 0), wmax);
                row = min(max(row, 0), hmax);
            }
            pp [j] = row * PITCH + col;
            wxh[j] = __float2half2_rn(ix - x0f);
            wyh[j] = __float2half2_rn(iy - y0f);
        }

        float s0 = 0.0f, s1 = 0.0f, s2 = 0.0f;
        #pragma unroll
        for (int hh = 0; hh < 2; ++hh) {
            uint2 q00[5], q01[5], q10[5], q11[5];
            #pragma unroll
            for (int j = 0; j < 5; ++j) {
                const int p = pp[hh * 5 + j];
                q00[j] = *reinterpret_cast<const uint2*>(simg + 4 * p);
                q01[j] = *reinterpret_cast<const uint2*>(simg + 4 * (p + 1));
                q10[j] = *reinterpret_cast<const uint2*>(simg + 4 * (p + PITCH));
                q11[j] = *reinterpret_cast<const uint2*>(simg + 4 * (p + PITCH + 1));
            }
            #pragma unroll
            for (int j = 0; j < 5; ++j) {
                const int rr = hh * 5 + j;
                const __half2 wx2 = wxh[rr], wy2 = wyh[rr];
                const __half2 a00 = u2h(q00[j].x), a01 = u2h(q01[j].x);
                const __half2 a10 = u2h(q10[j].x), a11 = u2h(q11[j].x);
                __half2 topA = __hfma2(wx2, __hsub2(a01, a00), a00);
                __half2 botA = __hfma2(wx2, __hsub2(a11, a10), a10);
                __half2 valA = __hfma2(wy2, __hsub2(botA, topA), topA);
                const __half2 b00 = u2h(q00[j].y), b01 = u2h(q01[j].y);
                const __half2 b10 = u2h(q10[j].y), b11 = u2h(q11[j].y);
                __half2 topB = __hfma2(wx2, __hsub2(b01, b00), b00);
                __half2 botB = __hfma2(wx2, __hsub2(b11, b10), b10);
                __half2 valB = __hfma2(wy2, __hsub2(botB, topB), topB);

                const float2 fA = __half22float2(valA);
                s0 += fA.x;
                s1 += fA.y;
                s2 += __low2float(valB);
            }
        }
        *reinterpret_cast<float4*>(&sacc[it * 4]) =
            make_float4(s0, s1, s2, 0.0f);

        tl += DT; win += DW;
        if (tl >= T) { tl -= T; ++win; }
    }
}

template<int W0, int G, int T>
__device__ __forceinline__ void band4(
    const int b, const int quad,
    const float* __restrict__ x,
    float* __restrict__ out,
    const float sx, const float sy,
    __half*  __restrict__ simg,
    float*   __restrict__ sacc,
    float*   __restrict__ rtab,
    float2*  __restrict__ sct,     // 2*T entries (dbuf)
    int*     __restrict__ sbb)     // 4 slots x 5 ints
{
    constexpr int TC   = T / 10;
    constexpr int ACCN = 3 * G * TC;
    const int tid   = threadIdx.x;
    const int slot0 = quad * 4;
    const int lane16 = tid & 15;
    const int rowB   = tid >> 4;

    const float CT  = 6.283185307179586f / 640.0f;
    const float LN001 = -4.605170185988091f;          // ln 0.01
    const float LSTEP = 4.0943445622221004f / 319.0f; // ln 60 / 319

    // ---- prologue: rtab, sctab buf0 (slot0), 4 bboxes ----
    if (tid < G * 10)
        rtab[tid] = 256.0f * expf(fmaf((float)(W0 * 10 + tid), LSTEP, LN001));
    if (tid >= 128 && tid < 128 + T) {
        const int u = tid - 128;
        const float th = (float)(slot0 * T + u) * CT;
        sct[u] = make_float2(sinf(th), cosf(th));
    }
    if (tid < 4) {
        const int th0 = (slot0 + tid) * T;
        const float tha = th0 * CT, thb = (th0 + T - 1) * CT;
        const float r_lo = expf(fmaf((float)(10 * W0),           LSTEP, LN001));
        const float r_hi = expf(fmaf((float)(10 * (W0 + G) - 1), LSTEP, LN001));
        const float plo = 256.0f * r_lo, phi = 256.0f * r_hi;
        const float sa = sinf(tha), sb = sinf(thb);
        const float ca = cosf(tha), cb = cosf(thb);
        const float smax = (tha < 1.5707965f && thb > 1.5707962f) ?  1.0f : fmaxf(sa, sb);
        const float smin = (tha < 4.7123892f && thb > 4.7123888f) ? -1.0f : fminf(sa, sb);
        const float cmax = fmaxf(ca, cb);
        const float cmin = (tha < 3.1415928f && thb > 3.1415925f) ? -1.0f : fminf(ca, cb);
        const float ixmin = fminf(fminf(plo*smin, phi*smin), fminf(plo*smax, phi*smax)) + sx;
        const float ixmax = fmaxf(fmaxf(plo*smin, phi*smin), fmaxf(plo*smax, phi*smax)) + sx;
        const float iymin = fminf(fminf(plo*cmin, phi*cmin), fminf(plo*cmax, phi*cmax)) + sy;
        const float iymax = fmaxf(fmaxf(plo*cmin, phi*cmin), fmaxf(plo*cmax, phi*cmax)) + sy;
        const int x_lo = max(0, (int)floorf(ixmin - 0.5f));
        const int x_hi = min(511, (int)ceilf(ixmax + 0.5f));
        const int y_lo = max(0, (int)floorf(iymin - 0.5f));
        const int y_hi = min(511, (int)ceilf(iymax + 0.5f));
        int* o = sbb + 5 * tid;
        o[0] = x_lo & ~3;
        o[1] = y_lo;
        o[2] = min(16, ((x_hi + 1 - (x_lo & ~3)) >> 2) + 1);
        o[3] = min(64, y_hi - y_lo + 2);
        o[4] = ((ixmin > 1.0f) && (ixmax < 510.0f) &&
                (iymin > 1.0f) && (iymax < 510.0f)) ? 1 : 0;
    }
    __syncthreads();

    const float* __restrict__ xb = x + (size_t)b * 3 * PLANE_;

    // ---- stage slot0 (issue upfront + write) ----
    {
        const int xs4 = sbb[0], y_lo = sbb[1], W4 = sbb[2], H = sbb[3];
        const int xb0 = xs4 + (lane16 << 2);
        if (lane16 < W4) {
            if (xb0 <= 508) {
                float4 v0[4], v1[4], v2[4];
                int rw[4];
                #pragma unroll
                for (int k = 0; k < 4; ++k) {
                    rw[k] = rowB + 16 * k;
                    if (rw[k] < H) {
                        const int ys = min(y_lo + rw[k], 511);
                        const float* __restrict__ r0 = xb + ys * 512 + xb0;
                        v0[k] = *reinterpret_cast<const float4*>(r0);
                        v1[k] = *reinterpret_cast<const float4*>(r0 + PLANE_);
                        v2[k] = *reinterpret_cast<const float4*>(r0 + 2 * PLANE_);
                    }
                }
                #pragma unroll
                for (int k = 0; k < 4; ++k) {
                    if (rw[k] < H) {
                        const int pix0 = rw[k] * PITCH + (lane16 << 2);
                        const float* a0 = reinterpret_cast<const float*>(&v0[k]);
                        const float* a1 = reinterpret_cast<const float*>(&v1[k]);
                        const float* a2 = reinterpret_cast<const float*>(&v2[k]);
                        #pragma unroll
                        for (int p = 0; p < 4; ++p)
                            store_px(simg, pix0 + p, a0[p], a1[p], a2[p]);
                    }
                }
            } else {
                #pragma unroll
                for (int k = 0; k < 4; ++k) {
                    const int rw = rowB + 16 * k;
                    if (rw < H) {
                        const int ys = min(y_lo + rw, 511);
                        const float* __restrict__ r0 = xb + ys * 512;
                        const int pix0 = rw * PITCH + (lane16 << 2);
                        #pragma unroll
                        for (int p = 0; p < 4; ++p) {
                            const int xs = min(xb0 + p, 511);
                            store_px(simg, pix0 + p,
                                     r0[xs], r0[PLANE_ + xs], r0[2 * PLANE_ + xs]);
                        }
                    }
                }
            }
        }
    }
    __syncthreads();

    float4 e0[4], e1[4], e2[4];
    #pragma unroll 1
    for (int i = 0; i < 4; ++i) {
        const int* bb = sbb + 5 * i;
        const int* nb = sbb + 5 * (i + 1);   // valid when i<3
        bool main1 = false;
        int  xb1 = 0;
        if (i < 3) {
            // issue next slot's loads into registers (early)
            xb1   = nb[0] + (lane16 << 2);
            main1 = (lane16 < nb[2]) && (xb1 <= 508);
            if (main1) {
                #pragma unroll
                for (int k = 0; k < 4; ++k) {
                    const int rw = rowB + 16 * k;
                    if (rw < nb[3]) {
                        const int ys = min(nb[1] + rw, 511);
                        const float* __restrict__ r0 = xb + ys * 512 + xb1;
                        e0[k] = *reinterpret_cast<const float4*>(r0);
                        e1[k] = *reinterpret_cast<const float4*>(r0 + PLANE_);
                        e2[k] = *reinterpret_cast<const float4*>(r0 + 2 * PLANE_);
                    }
                }
            }
            // rebuild sctab for next slot into the other buffer
            if (tid >= 192 && tid < 192 + T) {
                const int u = tid - 192;
                const float th = (float)((slot0 + i + 1) * T + u) * CT;
                sct[((i + 1) & 1) * T + u] = make_float2(sinf(th), cosf(th));
            }
        }

        // gather slot i (hides next slot's HBM latency)
        {
            const int wmax = (bb[2] << 2) - 2, hmax = bb[3] - 2;
            if (bb[4])
                gatherLoop<W0, G, T, true >(tid, simg, sacc, rtab,
                    reinterpret_cast<const float2*>(sct) + (i & 1) * T,
                    sx, sy, bb[0], bb[1], wmax, hmax);
            else
                gatherLoop<W0, G, T, false>(tid, simg, sacc, rtab,
                    reinterpret_cast<const float2*>(sct) + (i & 1) * T,
                    sx, sy, bb[0], bb[1], wmax, hmax);
        }
        __syncthreads();

        // out(slot i) || write tile(slot i+1)
        if (tid < ACCN) {
            const int c   = tid / (G * TC);
            const int rem = tid - c * (G * TC);
            const int win = rem / TC;
            const int tc  = rem - win * TC;
            const int base = (win * T + tc * 10) * 4 + c;
            float s = 0.0f;
            #pragma unroll
            for (int ph = 0; ph < 10; ++ph)
                s += sacc[base + ph * 4];
            out[(((size_t)b * 3 + c) * 32 + W0 + win) * 64 + (slot0 + i) * TC + tc] =
                s * 0.01f;
        }
        if (i < 3 && lane16 < nb[2]) {
            const int Hb = nb[3];
            if (main1) {
                #pragma unroll
                for (int k = 0; k < 4; ++k) {
                    const int rw = rowB + 16 * k;
                    if (rw < Hb) {
                        const int pix0 = rw * PITCH + (lane16 << 2);
                        const float* a0 = reinterpret_cast<const float*>(&e0[k]);
                        const float* a1 = reinterpret_cast<const float*>(&e1[k]);
                        const float* a2 = reinterpret_cast<const float*>(&e2[k]);
                        #pragma unroll
                        for (int p = 0; p < 4; ++p)
                            store_px(simg, pix0 + p, a0[p], a1[p], a2[p]);
                    }
                }
            } else {
                // rare right-edge: late scalar clamped loads
                #pragma unroll
                for (int k = 0; k < 4; ++k) {
                    const int rw = rowB + 16 * k;
                    if (rw < Hb) {
                        const int ys = min(nb[1] + rw, 511);
                        const float* __restrict__ r0 = xb + ys * 512;
                        const int pix0 = rw * PITCH + (lane16 << 2);
                        #pragma unroll
                        for (int p = 0; p < 4; ++p) {
                            const int xs = min(xb1 + p, 511);
                            store_px(simg, pix0 + p,
                                     r0[xs], r0[PLANE_ + xs], r0[2 * PLANE_ + xs]);
                        }
                    }
                }
            }
        }
        __syncthreads();
    }
}

__global__ __launch_bounds__(256, 4) void retina_polar_staged(
    const float* __restrict__ x,
    const float* __restrict__ lt,
    const float* __restrict__ grid,   // unused: grid is separable, rebuilt in LDS
    float* __restrict__ out)
{
    __shared__ __half  simg[TILEPIX * 4];   // 33792 B
    __shared__ float   sacc[1280];          //  5120 B
    __shared__ float   rtab[80];            //   320 B
    __shared__ float2  sct[80];             //   640 B (2 buffers x T<=40)
    __shared__ int     sbb[20];             //    80 B  -> total 39952 B

    const int bid = blockIdx.x;
    const int b   = bid / 36;
    const int r   = bid - b * 36;
    const float sx = fmaf(lt[b * 2 + 0], 256.0f, 255.5f);
    const float sy = fmaf(lt[b * 2 + 1], 256.0f, 255.5f);

    if      (r <  4) band4< 0, 8, 40>(b, r,      x, out, sx, sy, simg, sacc, rtab, sct, sbb);
    else if (r <  8) band4< 8, 7, 40>(b, r - 4,  x, out, sx, sy, simg, sacc, rtab, sct, sbb);
    else if (r < 12) band4<15, 5, 40>(b, r - 8,  x, out, sx, sy, simg, sacc, rtab, sct, sbb);
    else if (r < 16) band4<20, 4, 40>(b, r - 12, x, out, sx, sy, simg, sacc, rtab, sct, sbb);
    else if (r < 20) band4<24, 3, 40>(b, r - 16, x, out, sx, sy, simg, sacc, rtab, sct, sbb);
    else if (r < 24) band4<27, 2, 40>(b, r - 20, x, out, sx, sy, simg, sacc, rtab, sct, sbb);
    else if (r < 28) band4<29, 1, 40>(b, r - 24, x, out, sx, sy, simg, sacc, rtab, sct, sbb);
    else             band4<30, 2, 20>(b, r - 28, x, out, sx, sy, simg, sacc, rtab, sct, sbb);
}

extern "C" void kernel_launch(void* const* d_in, const int* in_sizes, int n_in,
                              void* d_out, int out_size, void* d_ws, size_t ws_size,
                              hipStream_t stream)
{
    const float* x    = (const float*)d_in[0];
    const float* lt   = (const float*)d_in[1];
    const float* grid = (const float*)d_in[2];
    float* out        = (float*)d_out;

    retina_polar_staged<<<dim3(B_ * 36), dim3(256), 0, stream>>>(x, lt, grid, out);
}